// Round 14
// baseline (98.775 us; speedup 1.0000x reference)
//
#include <hip/hip_runtime.h>
#include <hip/hip_bf16.h>

#define NSEN 4000
#define NP   4096
#define DIN  128
#define DOUT 128
#define EDIM 16
#define BATCH 8

typedef __attribute__((ext_vector_type(8))) short bf16x8;
typedef __attribute__((ext_vector_type(4))) float f32x4;

__device__ __forceinline__ unsigned short f2bf(float f) {
  unsigned int u = __float_as_uint(f);
  unsigned int r = (u + 0x7FFFu + ((u >> 16) & 1u)) >> 16;
  return (unsigned short)r;
}
__device__ __forceinline__ float bf2f(unsigned short s) {
  unsigned int u = ((unsigned int)s) << 16;
  return __uint_as_float(u);
}

__device__ __forceinline__ void gl_lds16(const void* g, void* l) {
  __builtin_amdgcn_global_load_lds((const __attribute__((address_space(1))) void*)g,
                                   (__attribute__((address_space(3))) void*)l, 16, 0, 0);
}

// ---------------- Kernel 1 (prep) -------------------------------------------------
// blocks 0..255:   yt[b*128+o][m] = bf16( (x @ W)[b,m,o] ), cols m>=NSEN -> 0
// blocks 256..263: split E1,E2 into hi/lo bf16 arrays (rows >= NSEN zeroed)
__global__ __launch_bounds__(512) void k_prep(const float* __restrict__ W,
                                              const float* __restrict__ x,
                                              const float* __restrict__ E1,
                                              const float* __restrict__ E2,
                                              unsigned short* __restrict__ yt,
                                              unsigned short* __restrict__ e1h,
                                              unsigned short* __restrict__ e1l,
                                              unsigned short* __restrict__ e2h,
                                              unsigned short* __restrict__ e2l) {
  const int bx = blockIdx.x;
  const int tid = threadIdx.x;

  if (bx >= 256) {
    // E hi/lo split: 65536 elems per tensor (incl. 4096-row pad), coalesced
    for (int i = (bx - 256) * 512 + tid; i < NP * EDIM; i += 8 * 512) {
      float v1 = (i < NSEN * EDIM) ? E1[i] : 0.f;
      unsigned short h1 = f2bf(v1);
      e1h[i] = h1;
      e1l[i] = f2bf(v1 - bf2f(h1));
      float v2 = (i < NSEN * EDIM) ? E2[i] : 0.f;
      unsigned short h2 = f2bf(v2);
      e2h[i] = h2;
      e2l[i] = f2bf(v2 - bf2f(h2));
    }
    return;
  }

  __shared__ __align__(16) unsigned short pool[34816];
  unsigned short* wlds = pool;            // [128][136] W^T bf16
  unsigned short* ylds = pool + 17408;    // [128][136] y^T bf16
  const int lane = tid & 63, wv = tid >> 6;
  const int lr = lane & 15, lq = lane >> 4;

  {
    const int fr = tid >> 5;   // 0..15
    const int o4 = tid & 31;   // 0..31
#pragma unroll
    for (int r8 = 0; r8 < 8; r8++) {
      const int f = fr + r8 * 16;
      float4 w4 = *(const float4*)&W[(size_t)f * DOUT + o4 * 4];
      wlds[(o4 * 4 + 0) * 136 + f] = f2bf(w4.x);
      wlds[(o4 * 4 + 1) * 136 + f] = f2bf(w4.y);
      wlds[(o4 * 4 + 2) * 136 + f] = f2bf(w4.z);
      wlds[(o4 * 4 + 3) * 136 + f] = f2bf(w4.w);
    }
  }
  __syncthreads();

  const int b  = bx >> 5;         // 0..7
  const int m0 = (bx & 31) * 128; // 0..3968
  const int mh = wv >> 2;         // 0..1 : 64-m half
  const int os = wv & 3;          // 0..3 : 32-o strip

  bf16x8 af[2][4];
#pragma unroll
  for (int ot = 0; ot < 2; ot++) {
    const int ob = os * 32 + ot * 16 + lr;
#pragma unroll
    for (int ks = 0; ks < 4; ks++)
      af[ot][ks] = *(const bf16x8*)&wlds[ob * 136 + ks * 32 + lq * 8];
  }

#pragma unroll
  for (int mt = 0; mt < 4; mt++) {
    const int mloc = mh * 64 + mt * 16;
    const int m = m0 + mloc + lr;
    bf16x8 bx8[4];
    if (m < NSEN) {
      const float* xp = &x[((size_t)b * NSEN + m) * DIN + lq * 8];
#pragma unroll
      for (int ks = 0; ks < 4; ks++) {
        float4 v0 = *(const float4*)(xp + ks * 32);
        float4 v1 = *(const float4*)(xp + ks * 32 + 4);
        bx8[ks][0] = (short)f2bf(v0.x); bx8[ks][1] = (short)f2bf(v0.y);
        bx8[ks][2] = (short)f2bf(v0.z); bx8[ks][3] = (short)f2bf(v0.w);
        bx8[ks][4] = (short)f2bf(v1.x); bx8[ks][5] = (short)f2bf(v1.y);
        bx8[ks][6] = (short)f2bf(v1.z); bx8[ks][7] = (short)f2bf(v1.w);
      }
    } else {
#pragma unroll
      for (int ks = 0; ks < 4; ks++)
#pragma unroll
        for (int j = 0; j < 8; j++) bx8[ks][j] = 0;
    }
#pragma unroll
    for (int ot = 0; ot < 2; ot++) {
      f32x4 c = (f32x4){0.f, 0.f, 0.f, 0.f};
#pragma unroll
      for (int ks = 0; ks < 4; ks++)
        c = __builtin_amdgcn_mfma_f32_16x16x32_bf16(af[ot][ks], bx8[ks], c, 0, 0, 0);
#pragma unroll
      for (int i = 0; i < 4; i++)
        ylds[(os * 32 + ot * 16 + lq * 4 + i) * 136 + mloc + lr] = f2bf(c[i]);
    }
  }
  __syncthreads();
#pragma unroll
  for (int s2 = 0; s2 < 4; s2++) {
    int c = s2 * 512 + tid;
    int row = c >> 4;
    int mc = c & 15;
    *(bf16x8*)&yt[(size_t)(b * 128 + row) * NP + m0 + mc * 8] =
        *(const bf16x8*)&ylds[row * 136 + mc * 8];
  }
}

// ---------------- Kernel 2: split-K GEMM with on-the-fly A generation -------------
// C = P @ yt^T, P[m][k] = exp(relu(E1[m]·E2[k])) generated in-kernel (hi/lo MFMA)
// directly into swizzled LDS. B (yt) staged via global_load_lds. R12 2-phase loop.
// Partial rowsums accumulated in registers; nt==0 blocks write them (deterministic).
__global__ __launch_bounds__(512, 2) void k_gemm(const unsigned short* __restrict__ e1h,
                                                 const unsigned short* __restrict__ e1l,
                                                 const unsigned short* __restrict__ e2h,
                                                 const unsigned short* __restrict__ e2l,
                                                 const unsigned short* __restrict__ Bt,
                                                 unsigned short* __restrict__ part,
                                                 float* __restrict__ rowsumP,
                                                 int nsteps) {
  __shared__ __align__(16) unsigned short smem[65536];  // 128 KB
  unsigned short* tA0 = smem;           // 2 x 16384 shorts
  unsigned short* tB0 = smem + 32768;   // 2 x 16384 shorts
  const int tid = threadIdx.x;
  const int lane = tid & 63, wv = tid >> 6;
  const int wr = wv >> 2, wcn = wv & 3;   // 2M x 4N waves, wave tile 128x64
  const int lr = lane & 15, lq = lane >> 4;
  const int kh = blockIdx.x & 3;          // x = mt*4 + kh: B-panel sharers pair on XCDs
  const int m0 = (blockIdx.x >> 2) * 256;
  const int n0c = blockIdx.y * 256;
  const int kb0 = kh * nsteps * 64;

  // E1 generator fragments (loop-invariant): wave's gen rows = m0 + wv*32 + mt*16 + lr
  bf16x8 e1f[2];
#pragma unroll
  for (int mt = 0; mt < 2; mt++) {
    const size_t m = m0 + wv * 32 + mt * 16 + lr;
    e1f[mt] = (lq < 2) ? *(const bf16x8*)&e1h[m * EDIM + lq * 8]
                       : *(const bf16x8*)&e1l[m * EDIM + (lq & 1) * 8];
  }

  float rsacc[2] = {0.f, 0.f};

  f32x4 acc[8][4];
#pragma unroll
  for (int p = 0; p < 8; p++)
#pragma unroll
    for (int q = 0; q < 4; q++) acc[p][q] = (f32x4){0.f, 0.f, 0.f, 0.f};

  // B staging: 4 x 16B chunks per thread (2048 chunks = 256 rows x 8), swizzled src
#define STAGE_B(bufi, kb)                                                               \
  {                                                                                     \
    _Pragma("unroll")                                                                   \
    for (int s = 0; s < 4; s++) {                                                       \
      int idx = s * 512 + tid;                                                          \
      int row = idx >> 3;                                                               \
      int kc = ((idx & 7) ^ (row & 7)) << 3;                                            \
      gl_lds16(&Bt[(size_t)(n0c + row) * NP + (kb) + kc], &tB0[(bufi)*16384 + idx*8]);  \
    }                                                                                   \
  }

  // A generation: wave gen-rows wv*32..+32, all 64 k. Writes match read swizzle:
  // short idx = mloc*64 + ((k>>3) ^ (mloc&7))*8 + (k&7)
#define GEN_A(bufi, kb)                                                                 \
  {                                                                                     \
    bf16x8 ga1[4], ga2[4];                                                              \
    _Pragma("unroll")                                                                   \
    for (int kt = 0; kt < 4; kt++) {                                                    \
      const size_t kr = (kb) + kt * 16 + lr;                                            \
      ga1[kt] = *(const bf16x8*)&e2h[kr * EDIM + (lq & 1) * 8];                         \
      bf16x8 z = {0, 0, 0, 0, 0, 0, 0, 0};                                              \
      if (lq < 2) z = *(const bf16x8*)&e2l[kr * EDIM + lq * 8];                         \
      ga2[kt] = z;                                                                      \
    }                                                                                   \
    _Pragma("unroll")                                                                   \
    for (int kt = 0; kt < 4; kt++) {                                                    \
      _Pragma("unroll")                                                                 \
      for (int mt = 0; mt < 2; mt++) {                                                  \
        f32x4 c = (f32x4){0.f, 0.f, 0.f, 0.f};                                          \
        c = __builtin_amdgcn_mfma_f32_16x16x32_bf16(ga1[kt], e1f[mt], c, 0, 0, 0);      \
        c = __builtin_amdgcn_mfma_f32_16x16x32_bf16(ga2[kt], e1f[mt], c, 0, 0, 0);      \
        const int kgb = (kb) + kt * 16 + lq * 4;                                        \
        float pv[4];                                                                    \
        _Pragma("unroll")                                                               \
        for (int i = 0; i < 4; i++)                                                     \
          pv[i] = (kgb + i < NSEN) ? __expf(fmaxf(c[i], 0.f)) : 0.f;                    \
        rsacc[mt] += (pv[0] + pv[1]) + (pv[2] + pv[3]);                                 \
        const int mloc = wv * 32 + mt * 16 + lr;                                        \
        const int chs = (kt * 2 + (lq >> 1)) ^ (mloc & 7);                              \
        uint2 w;                                                                        \
        w.x = (unsigned)f2bf(pv[0]) | ((unsigned)f2bf(pv[1]) << 16);                    \
        w.y = (unsigned)f2bf(pv[2]) | ((unsigned)f2bf(pv[3]) << 16);                    \
        *(uint2*)&tA0[(bufi) * 16384 + mloc * 64 + chs * 8 + (lq & 1) * 4] = w;         \
      }                                                                                 \
    }                                                                                   \
  }

  // prologue: build tile 0
  GEN_A(0, kb0);
  STAGE_B(0, kb0);
  asm volatile("s_waitcnt lgkmcnt(0)" ::: "memory");  // gen writes of buf0 drained

  for (int it = 0; it < nsteps; ++it) {
    const int cur = it & 1;
    if (it < nsteps - 1) {
      GEN_A(cur ^ 1, kb0 + (it + 1) * 64);   // gen first: its E2-waits must not drain B
      STAGE_B(cur ^ 1, kb0 + (it + 1) * 64);
      asm volatile("s_waitcnt vmcnt(4)" ::: "memory");  // cur's B landed; nxt's in flight
    } else {
      asm volatile("s_waitcnt vmcnt(0)" ::: "memory");
    }
    __builtin_amdgcn_s_barrier();

    {  // k-slice 0
      const int koff = (lq * 8) ^ ((lr & 7) << 3);
      bf16x8 af[8], bf[4];
#pragma unroll
      for (int p = 0; p < 8; p++)
        af[p] = *(const bf16x8*)&tA0[cur * 16384 + (wr * 128 + p * 16 + lr) * 64 + koff];
#pragma unroll
      for (int q = 0; q < 4; q++)
        bf[q] = *(const bf16x8*)&tB0[cur * 16384 + (wcn * 64 + q * 16 + lr) * 64 + koff];
      asm volatile("s_waitcnt lgkmcnt(0)" ::: "memory");
      __builtin_amdgcn_sched_barrier(0);
      __builtin_amdgcn_s_setprio(1);
#pragma unroll
      for (int p = 0; p < 8; p++)
#pragma unroll
        for (int q = 0; q < 4; q++)
          acc[p][q] = __builtin_amdgcn_mfma_f32_16x16x32_bf16(af[p], bf[q], acc[p][q], 0, 0, 0);
      __builtin_amdgcn_s_setprio(0);
    }
    {  // k-slice 1
      const int koff = (32 + lq * 8) ^ ((lr & 7) << 3);
      bf16x8 af[8], bf[4];
#pragma unroll
      for (int p = 0; p < 8; p++)
        af[p] = *(const bf16x8*)&tA0[cur * 16384 + (wr * 128 + p * 16 + lr) * 64 + koff];
#pragma unroll
      for (int q = 0; q < 4; q++)
        bf[q] = *(const bf16x8*)&tB0[cur * 16384 + (wcn * 64 + q * 16 + lr) * 64 + koff];
      asm volatile("s_waitcnt lgkmcnt(0)" ::: "memory");
      __builtin_amdgcn_sched_barrier(0);
      __builtin_amdgcn_s_setprio(1);
#pragma unroll
      for (int p = 0; p < 8; p++)
#pragma unroll
        for (int q = 0; q < 4; q++)
          acc[p][q] = __builtin_amdgcn_mfma_f32_16x16x32_bf16(af[p], bf[q], acc[p][q], 0, 0, 0);
      __builtin_amdgcn_s_setprio(0);
    }
    __builtin_amdgcn_s_barrier();  // cur fully consumed -> reusable
  }
#undef STAGE_B
#undef GEN_A

  // rowsum partials: reduce over lq groups (k coverage), write once per row
#pragma unroll
  for (int mt = 0; mt < 2; mt++) {
    rsacc[mt] += __shfl_xor(rsacc[mt], 16, 64);
    rsacc[mt] += __shfl_xor(rsacc[mt], 32, 64);
  }
  if (blockIdx.y == 0 && lq == 0) {
#pragma unroll
    for (int mt = 0; mt < 2; mt++)
      rowsumP[kh * NP + m0 + wv * 32 + mt * 16 + lr] = rsacc[mt];
  }

  // epilogue: bf16 partial store part[kh][m][j]
  unsigned short* pdst = part + ((size_t)kh << 22);
#pragma unroll
  for (int p = 0; p < 8; p++)
#pragma unroll
    for (int q = 0; q < 4; q++) {
      const int col = n0c + wcn * 64 + q * 16 + lr;
#pragma unroll
      for (int i = 0; i < 4; i++) {
        const int row = m0 + wr * 128 + p * 16 + lq * 4 + i;
        pdst[(size_t)row * 1024 + col] = f2bf(acc[p][q][i]);
      }
    }
}

// ---------------- Kernel 3: out = relu((sum_kh part)*rinv + bias) -----------------
__global__ __launch_bounds__(256) void k_fin(const unsigned short* __restrict__ part,
                                             const float* __restrict__ rowsumP,
                                             const float* __restrict__ bias,
                                             float* __restrict__ out, int ksl) {
  const int tid = threadIdx.x;
  const int nl = tid >> 4;
  const int ch = tid & 15;
  const int n  = blockIdx.x * 16 + nl;   // < 4000
  const int b  = blockIdx.y;
  const int j  = b * 128 + ch * 8;

  float rsum = 0.f;
  for (int kh = 0; kh < ksl; kh++) rsum += rowsumP[kh * NP + n];
  const float rv = 1.f / rsum;

  float s[8] = {0.f, 0.f, 0.f, 0.f, 0.f, 0.f, 0.f, 0.f};
  for (int kh = 0; kh < ksl; kh++) {
    bf16x8 pv = *(const bf16x8*)&part[((size_t)kh << 22) + (size_t)n * 1024 + j];
#pragma unroll
    for (int jj = 0; jj < 8; jj++) s[jj] += bf2f((unsigned short)pv[jj]);
  }
  float4 bb0 = *(const float4*)&bias[ch * 8];
  float4 bb1 = *(const float4*)&bias[ch * 8 + 4];
  float r[8];
#pragma unroll
  for (int jj = 0; jj < 8; jj++) {
    float bbj = (jj < 4) ? ((const float*)&bb0)[jj] : ((const float*)&bb1)[jj - 4];
    r[jj] = fmaxf(s[jj] * rv + bbj, 0.f);
  }
  float* op = &out[((size_t)b * NSEN + n) * DOUT + ch * 8];
  *(float4*)op       = make_float4(r[0], r[1], r[2], r[3]);
  *(float4*)(op + 4) = make_float4(r[4], r[5], r[6], r[7]);
}

// ---------------- launch -----------------------------------------------------------
extern "C" void kernel_launch(void* const* d_in, const int* in_sizes, int n_in,
                              void* d_out, int out_size, void* d_ws, size_t ws_size,
                              hipStream_t stream) {
  const float* x    = (const float*)d_in[0];
  const float* E1   = (const float*)d_in[1];
  const float* E2   = (const float*)d_in[2];
  const float* W    = (const float*)d_in[3];
  const float* bias = (const float*)d_in[4];
  float* out = (float*)d_out;

  char* ws = (char*)d_ws;
  // layout: yt 8388608 | e1h/e1l/e2h/e2l 4x131072 | rowsumP 65536 | part 33554432 (~42.5 MiB)
  unsigned short* yt   = (unsigned short*)(ws);
  unsigned short* e1h  = (unsigned short*)(ws + 8388608);
  unsigned short* e1l  = (unsigned short*)(ws + 8388608 + 131072);
  unsigned short* e2h  = (unsigned short*)(ws + 8388608 + 262144);
  unsigned short* e2l  = (unsigned short*)(ws + 8388608 + 393216);
  float* rowsumP       = (float*)(ws + 8388608 + 524288);
  unsigned short* part = (unsigned short*)(ws + 8388608 + 524288 + 65536);

  const int KS = 4, nsteps = 64 / KS;

  k_prep<<<dim3(264), dim3(512), 0, stream>>>(W, x, E1, E2, yt, e1h, e1l, e2h, e2l);
  k_gemm<<<dim3(KS * 16, 4), dim3(512), 0, stream>>>(e1h, e1l, e2h, e2l, yt, part, rowsumP, nsteps);
  k_fin<<<dim3(250, BATCH), dim3(256), 0, stream>>>(part, rowsumP, bias, out, KS);
}

// Round 15
// 76.414 us; speedup vs baseline: 1.2926x; 1.2926x over previous
//
#include <hip/hip_runtime.h>
#include <hip/hip_bf16.h>

#define NSEN 4000
#define NP   4096
#define DIN  128
#define DOUT 128
#define EDIM 16
#define BATCH 8

typedef __attribute__((ext_vector_type(8))) short bf16x8;
typedef __attribute__((ext_vector_type(4))) float f32x4;

__device__ __forceinline__ unsigned short f2bf(float f) {
  unsigned int u = __float_as_uint(f);
  unsigned int r = (u + 0x7FFFu + ((u >> 16) & 1u)) >> 16;
  return (unsigned short)r;
}
__device__ __forceinline__ float bf2f(unsigned short s) {
  unsigned int u = ((unsigned int)s) << 16;
  return __uint_as_float(u);
}

__device__ __forceinline__ void gl_lds16(const void* g, void* l) {
  __builtin_amdgcn_global_load_lds((const __attribute__((address_space(1))) void*)g,
                                   (__attribute__((address_space(3))) void*)l, 16, 0, 0);
}

// ---------------- Kernel 1 (merged prep) -----------------------------------------
// blocks 0..249:   P = exp(relu(E1 @ E2^T)) unnorm -> adjp bf16 ; rinv = 1/rowsum
// blocks 250..505: yt[b*128+o][m] = bf16( (x @ W)[b,m,o] ), cols m>=NSEN -> 0
__global__ __launch_bounds__(512) void k_prep(const float* __restrict__ E1,
                                              const float* __restrict__ E2,
                                              const float* __restrict__ W,
                                              const float* __restrict__ x,
                                              unsigned short* __restrict__ adjp,
                                              float* __restrict__ rinv,
                                              unsigned short* __restrict__ yt) {
  __shared__ float rsum[8][16];
  __shared__ __align__(16) unsigned short pool[34816];  // y-branch: wlds+ylds
  const int bx = blockIdx.x;
  const int tid = threadIdx.x;
  const int lane = tid & 63, wv = tid >> 6;
  const int lr = lane & 15, lq = lane >> 4;

  if (bx >= 250) {
    unsigned short* wlds = pool;            // [128][136] W^T bf16
    unsigned short* ylds = pool + 17408;    // [128][136] y^T bf16
    {
      const int fr = tid >> 5;   // 0..15
      const int o4 = tid & 31;   // 0..31
#pragma unroll
      for (int r8 = 0; r8 < 8; r8++) {
        const int f = fr + r8 * 16;
        float4 w4 = *(const float4*)&W[(size_t)f * DOUT + o4 * 4];
        wlds[(o4 * 4 + 0) * 136 + f] = f2bf(w4.x);
        wlds[(o4 * 4 + 1) * 136 + f] = f2bf(w4.y);
        wlds[(o4 * 4 + 2) * 136 + f] = f2bf(w4.z);
        wlds[(o4 * 4 + 3) * 136 + f] = f2bf(w4.w);
      }
    }
    __syncthreads();

    const int yi = bx - 250;        // 0..255
    const int b  = yi >> 5;         // 0..7
    const int m0 = (yi & 31) * 128; // 0..3968
    const int mh = wv >> 2;         // 0..1 : 64-m half
    const int os = wv & 3;          // 0..3 : 32-o strip

    bf16x8 af[2][4];
#pragma unroll
    for (int ot = 0; ot < 2; ot++) {
      const int ob = os * 32 + ot * 16 + lr;
#pragma unroll
      for (int ks = 0; ks < 4; ks++)
        af[ot][ks] = *(const bf16x8*)&wlds[ob * 136 + ks * 32 + lq * 8];
    }

#pragma unroll
    for (int mt = 0; mt < 4; mt++) {
      const int mloc = mh * 64 + mt * 16;
      const int m = m0 + mloc + lr;
      bf16x8 bx8[4];
      if (m < NSEN) {
        const float* xp = &x[((size_t)b * NSEN + m) * DIN + lq * 8];
#pragma unroll
        for (int ks = 0; ks < 4; ks++) {
          float4 v0 = *(const float4*)(xp + ks * 32);
          float4 v1 = *(const float4*)(xp + ks * 32 + 4);
          bx8[ks][0] = (short)f2bf(v0.x); bx8[ks][1] = (short)f2bf(v0.y);
          bx8[ks][2] = (short)f2bf(v0.z); bx8[ks][3] = (short)f2bf(v0.w);
          bx8[ks][4] = (short)f2bf(v1.x); bx8[ks][5] = (short)f2bf(v1.y);
          bx8[ks][6] = (short)f2bf(v1.z); bx8[ks][7] = (short)f2bf(v1.w);
        }
      } else {
#pragma unroll
        for (int ks = 0; ks < 4; ks++)
#pragma unroll
          for (int j = 0; j < 8; j++) bx8[ks][j] = 0;
      }
#pragma unroll
      for (int ot = 0; ot < 2; ot++) {
        f32x4 c = (f32x4){0.f, 0.f, 0.f, 0.f};
#pragma unroll
        for (int ks = 0; ks < 4; ks++)
          c = __builtin_amdgcn_mfma_f32_16x16x32_bf16(af[ot][ks], bx8[ks], c, 0, 0, 0);
#pragma unroll
        for (int i = 0; i < 4; i++)
          ylds[(os * 32 + ot * 16 + lq * 4 + i) * 136 + mloc + lr] = f2bf(c[i]);
      }
    }
    __syncthreads();
#pragma unroll
    for (int s2 = 0; s2 < 4; s2++) {
      int c = s2 * 512 + tid;
      int row = c >> 4;
      int mc = c & 15;
      *(bf16x8*)&yt[(size_t)(b * 128 + row) * NP + m0 + mc * 8] =
          *(const bf16x8*)&ylds[row * 136 + mc * 8];
    }
    return;
  }

  // ---- adjacency rows n0..n0+15 (MFMA hi/lo split, direct stores) ----
  const int n0 = bx * 16;

  float a[8];
  {
    const float* e1p = &E1[(size_t)(n0 + lr) * EDIM + (lq & 1) * 8];
    *(float4*)&a[0] = *(const float4*)e1p;
    *(float4*)&a[4] = *(const float4*)(e1p + 4);
  }
  bf16x8 af1, af2;
#pragma unroll
  for (int j = 0; j < 8; j++) {
    unsigned short hs = f2bf(a[j]);
    af1[j] = (short)hs;
    float lo = a[j] - bf2f(hs);
    af2[j] = (lq < 2) ? (short)f2bf(lo) : (short)0;
  }

  float rs[4] = {0.f, 0.f, 0.f, 0.f};
  for (int t = wv; t < NSEN / 16; t += 8) {
    const int m = t * 16 + lr;
    float bv[8];
    const float* e2p = &E2[(size_t)m * EDIM + (lq & 1) * 8];
    *(float4*)&bv[0] = *(const float4*)e2p;
    *(float4*)&bv[4] = *(const float4*)(e2p + 4);
    bf16x8 bfrag;
#pragma unroll
    for (int j = 0; j < 8; j++) {
      unsigned short hs = f2bf(bv[j]);
      if (lq < 2) bfrag[j] = (short)hs;
      else        bfrag[j] = (short)f2bf(bv[j] - bf2f(hs));
    }
    f32x4 c = (f32x4){0.f, 0.f, 0.f, 0.f};
    c = __builtin_amdgcn_mfma_f32_16x16x32_bf16(af1, bfrag, c, 0, 0, 0);
    c = __builtin_amdgcn_mfma_f32_16x16x32_bf16(af2, bfrag, c, 0, 0, 0);
#pragma unroll
    for (int i = 0; i < 4; i++) {
      float p = __expf(fmaxf(c[i], 0.f));
      rs[i] += p;
      adjp[(size_t)(n0 + lq * 4 + i) * NP + t * 16 + lr] = f2bf(p);
    }
  }
  for (int i = tid; i < 16 * (NP - NSEN); i += 512) {
    int r = i / (NP - NSEN), c = i % (NP - NSEN);
    adjp[(size_t)(n0 + r) * NP + NSEN + c] = 0;
  }
#pragma unroll
  for (int i = 0; i < 4; i++) {
    rs[i] += __shfl_xor(rs[i], 1, 64);
    rs[i] += __shfl_xor(rs[i], 2, 64);
    rs[i] += __shfl_xor(rs[i], 4, 64);
    rs[i] += __shfl_xor(rs[i], 8, 64);
  }
  if (lr == 0) {
#pragma unroll
    for (int i = 0; i < 4; i++) rsum[wv][lq * 4 + i] = rs[i];
  }
  __syncthreads();
  if (tid < 16) {
    float s = 0.f;
#pragma unroll
    for (int w = 0; w < 8; w++) s += rsum[w][tid];
    rinv[n0 + tid] = 1.0f / s;
  }
}

// ---------------- Kernel 2: full-K GEMM + fused elementwise epilogue -------------
// out[b][n][o] = relu( (P @ yt^T)[n][b*128+o] * rinv[n] + bias[o] )
// R5-proven loop: BM=64, BN=128, BK=64, 256 thr (2x2 waves, wave tile 32x64),
// 3-buffer 72KB LDS depth-2 prefetch, counted vmcnt(12), split lgkmcnt, setprio,
// XOR-swizzled LDS via pre-swizzled source. grid (64,8) x-major: the 8 batch
// blocks of each A-panel share an XCD (bijective). No part buffer, no 3rd kernel.
__global__ __launch_bounds__(256, 2) void k_gemm(const unsigned short* __restrict__ A,
                                                 const unsigned short* __restrict__ Bt,
                                                 const float* __restrict__ rinv,
                                                 const float* __restrict__ bias,
                                                 float* __restrict__ out) {
  __shared__ __align__(16) unsigned short smem[36864];  // 72 KB: A 3x4096 | B 3x8192
  const int tid = threadIdx.x;
  const int lane = tid & 63, wv = tid >> 6;
  const int wr = wv >> 1, wc = wv & 1;     // 2 x 2 wave grid, wave tile 32x64
  const int lr = lane & 15, lq = lane >> 4;
  const int m0 = blockIdx.x * 64;
  const int b  = blockIdx.y;
  const int c0 = b * 128;
  unsigned short* tA0 = smem;           // 3 * 4096
  unsigned short* tB0 = smem + 12288;   // 3 * 8192

  f32x4 acc[2][4];
#pragma unroll
  for (int p = 0; p < 2; p++)
#pragma unroll
    for (int q = 0; q < 4; q++) acc[p][q] = (f32x4){0.f, 0.f, 0.f, 0.f};

#define STAGE(bufi, kb)                                                              \
  {                                                                                  \
    _Pragma("unroll")                                                                \
    for (int s = 0; s < 2; s++) {                                                    \
      int idx = s * 256 + tid;                                                       \
      int row = idx >> 3;                                                            \
      int kc = ((idx & 7) ^ (row & 7)) << 3;                                         \
      gl_lds16(&A[(size_t)(m0 + row) * NP + (kb) + kc], &tA0[(bufi)*4096 + idx*8]);  \
    }                                                                                \
    _Pragma("unroll")                                                                \
    for (int s = 0; s < 4; s++) {                                                    \
      int idx = s * 256 + tid;                                                       \
      int row = idx >> 3;                                                            \
      int kc = ((idx & 7) ^ (row & 7)) << 3;                                         \
      gl_lds16(&Bt[(size_t)(c0 + row) * NP + (kb) + kc], &tB0[(bufi)*8192 + idx*8]); \
    }                                                                                \
  }

  STAGE(0, 0);
  STAGE(1, 64);

  int cur = 0;
  for (int it = 0; it < 64; ++it) {
    if (it < 62) {
      int nb = cur + 2; if (nb >= 3) nb -= 3;
      STAGE(nb, (it + 2) * 64);
      asm volatile("s_waitcnt vmcnt(12)" ::: "memory");  // cur's 6 landed; 12 in flight
    } else if (it == 62) {
      asm volatile("s_waitcnt vmcnt(6)" ::: "memory");
    } else {
      asm volatile("s_waitcnt vmcnt(0)" ::: "memory");
    }
    __builtin_amdgcn_s_barrier();

    bf16x8 af0[2], bf0[4], af1[2], bf1[4];
    {
      const int koff0 = (lq * 8) ^ ((lr & 7) << 3);
#pragma unroll
      for (int p = 0; p < 2; p++)
        af0[p] = *(const bf16x8*)&tA0[cur * 4096 + (wr * 32 + p * 16 + lr) * 64 + koff0];
#pragma unroll
      for (int q = 0; q < 4; q++)
        bf0[q] = *(const bf16x8*)&tB0[cur * 8192 + (wc * 64 + q * 16 + lr) * 64 + koff0];
    }
    __builtin_amdgcn_sched_barrier(0);  // keep sk0 reads first in issue order
    {
      const int koff1 = (32 + lq * 8) ^ ((lr & 7) << 3);
#pragma unroll
      for (int p = 0; p < 2; p++)
        af1[p] = *(const bf16x8*)&tA0[cur * 4096 + (wr * 32 + p * 16 + lr) * 64 + koff1];
#pragma unroll
      for (int q = 0; q < 4; q++)
        bf1[q] = *(const bf16x8*)&tB0[cur * 8192 + (wc * 64 + q * 16 + lr) * 64 + koff1];
    }
    asm volatile("s_waitcnt lgkmcnt(6)" ::: "memory");  // sk0's 6 reads done
    __builtin_amdgcn_sched_barrier(0);
    __builtin_amdgcn_s_setprio(1);
#pragma unroll
    for (int p = 0; p < 2; p++)
#pragma unroll
      for (int q = 0; q < 4; q++)
        acc[p][q] = __builtin_amdgcn_mfma_f32_16x16x32_bf16(af0[p], bf0[q], acc[p][q], 0, 0, 0);
    asm volatile("s_waitcnt lgkmcnt(0)" ::: "memory");
    __builtin_amdgcn_sched_barrier(0);
#pragma unroll
    for (int p = 0; p < 2; p++)
#pragma unroll
      for (int q = 0; q < 4; q++)
        acc[p][q] = __builtin_amdgcn_mfma_f32_16x16x32_bf16(af1[p], bf1[q], acc[p][q], 0, 0, 0);
    __builtin_amdgcn_s_setprio(0);
    __builtin_amdgcn_s_barrier();
    cur = cur + 1; if (cur >= 3) cur = 0;
  }
#undef STAGE

  // ---- fused elementwise epilogue: out = relu(acc * rinv[n] + bias[o]) ----
#pragma unroll
  for (int p = 0; p < 2; p++) {
    float rv[4];
#pragma unroll
    for (int i = 0; i < 4; i++)
      rv[i] = rinv[m0 + wr * 32 + p * 16 + lq * 4 + i];
#pragma unroll
    for (int q = 0; q < 4; q++) {
      const int o = wc * 64 + q * 16 + lr;
      const float bb = bias[o];
#pragma unroll
      for (int i = 0; i < 4; i++) {
        const int n = m0 + wr * 32 + p * 16 + lq * 4 + i;
        if (n < NSEN)
          out[((size_t)b * NSEN + n) * DOUT + o] = fmaxf(acc[p][q][i] * rv[i] + bb, 0.f);
      }
    }
  }
}

// ---------------- launch ---------------------------------------------------------
extern "C" void kernel_launch(void* const* d_in, const int* in_sizes, int n_in,
                              void* d_out, int out_size, void* d_ws, size_t ws_size,
                              hipStream_t stream) {
  const float* x    = (const float*)d_in[0];
  const float* E1   = (const float*)d_in[1];
  const float* E2   = (const float*)d_in[2];
  const float* W    = (const float*)d_in[3];
  const float* bias = (const float*)d_in[4];
  float* out = (float*)d_out;

  char* ws = (char*)d_ws;
  // layout: adjp 33554432 | yt 8388608 | rinv 16384  (~42 MiB)
  unsigned short* adjp = (unsigned short*)(ws);
  unsigned short* yt   = (unsigned short*)(ws + 33554432);
  float*          rinv = (float*)(ws + 33554432 + 8388608);

  k_prep<<<dim3(506), dim3(512), 0, stream>>>(E1, E2, W, x, adjp, rinv, yt);
  k_gemm<<<dim3(NP / 64, BATCH), dim3(256), 0, stream>>>(adjp, yt, rinv, bias, out);
}